// Round 3
// baseline (182.887 us; speedup 1.0000x reference)
//
#include <hip/hip_runtime.h>
#include <math.h>

#define T_ 30
#define C_ 512
#define N_ 784      // 28*28 = 49 tiles of 16
#define NA_ 800     // aT row pitch (25 ksteps of 32)
#define SPITCH 72   // per-wave stage row pitch (ushorts) for one 64-c half
#define EPSV 1e-12f

typedef __attribute__((ext_vector_type(8))) short bf16x8;
typedef __attribute__((ext_vector_type(4))) float f32x4;

__device__ __forceinline__ unsigned short f2bf(float f) {
    union { float f; unsigned int u; } v; v.f = f;
    unsigned int r = (v.u + 0x7FFFu + ((v.u >> 16) & 1u)) >> 16;  // RNE
    return (unsigned short)r;
}
__device__ __forceinline__ float bf2f(unsigned short h) {
    union { unsigned int u; float f; } v; v.u = ((unsigned int)h) << 16;
    return v.f;
}

// wh/wl: split-precision bf16 of w, layout [k][c]
__global__ void k_prep(const float* __restrict__ w, unsigned short* __restrict__ wh,
                       unsigned short* __restrict__ wl) {
    int idx = blockIdx.x * 256 + threadIdx.x;  // 0..32767
    float v = w[idx];
    unsigned short h = f2bf(v);
    wh[idx] = h;
    wl[idx] = f2bf(v - bf2f(h));
}

// Fused invnorm + logits (3-product split-bf16 MFMA) + softmax + aT + asum.
// grid (49, 30), 256 thr. Block: 16 n x 64 k, c-reduction split over 4 waves.
// v3: half-c staging halves LDS 33.8->18.4 KB => 8 blocks/CU (was 4).
// Wave-private stage (in-order DS within wave => no barrier around half reuse).
__global__ __launch_bounds__(256, 8) void k_assign(
    const float* __restrict__ x, const unsigned short* __restrict__ wh,
    const unsigned short* __restrict__ wl, const float* __restrict__ b,
    unsigned short* __restrict__ aT, float* __restrict__ asum)
{
    // stage: xh/xl [4 w][16 n][SPITCH] ushort (one 64-c half per wave at a time)
    // red (union, reused after MFMA): [4 w][16 n][68 k] f32 = 17408 B
    __shared__ __align__(16) char smem[2 * 4 * 16 * SPITCH * 2];  // 18432 B
    unsigned short* xh = (unsigned short*)smem;
    unsigned short* xl = xh + 4 * 16 * SPITCH;
    float* red = (float*)smem;
    __shared__ float ssq[4][16];

    int t = blockIdx.y, n0 = blockIdx.x * 16;
    int tid = threadIdx.x;
    int w = tid >> 6, L = tid & 63, lid = L & 15, quad = L >> 4;
    int cbase = w * 128;            // wave-private c-slice [cbase, cbase+128)
    int nseg = (L & 3) * 4;         // n offset 0/4/8/12
    int crow = L >> 2;              // 0..15

    const float* xb = x + (size_t)t * C_ * N_ + n0 + nseg;
    unsigned short* shh = xh + w * 16 * SPITCH;
    unsigned short* shl = xl + w * 16 * SPITCH;
    const unsigned short* wha = wh + (size_t)lid * C_ + cbase + quad * 8;
    const unsigned short* wla = wl + (size_t)lid * C_ + cbase + quad * 8;

    float bk = b[L];
    float ss0 = 0.f, ss1 = 0.f, ss2 = 0.f, ss3 = 0.f;
    f32x4 acc[4];
    #pragma unroll
    for (int mt = 0; mt < 4; ++mt)
        #pragma unroll
        for (int r = 0; r < 4; ++r) acc[mt][r] = 0.f;

    #pragma unroll
    for (int half = 0; half < 2; ++half) {
        // load this half's 4 rows per thread (batched, in flight together)
        float4 q[4];
        #pragma unroll
        for (int p = 0; p < 4; ++p)
            q[p] = *reinterpret_cast<const float4*>(
                xb + (size_t)(cbase + half * 64 + p * 16 + crow) * N_);
        // stage (transpose + hi/lo split), accumulate sumsq
        #pragma unroll
        for (int p = 0; p < 4; ++p) {
            int cl = p * 16 + crow;
            float vv[4] = {q[p].x, q[p].y, q[p].z, q[p].w};
            ss0 = fmaf(vv[0], vv[0], ss0); ss1 = fmaf(vv[1], vv[1], ss1);
            ss2 = fmaf(vv[2], vv[2], ss2); ss3 = fmaf(vv[3], vv[3], ss3);
            #pragma unroll
            for (int j = 0; j < 4; ++j) {
                unsigned short h = f2bf(vv[j]);
                shh[(nseg + j) * SPITCH + cl] = h;
                shl[(nseg + j) * SPITCH + cl] = f2bf(vv[j] - bf2f(h));
            }
        }
        // MFMA over this half (reads only this wave's own stage rows)
        #pragma unroll
        for (int ks2 = 0; ks2 < 2; ++ks2) {
            bf16x8 bh = *reinterpret_cast<const bf16x8*>(
                &shh[lid * SPITCH + ks2 * 32 + quad * 8]);
            bf16x8 bl = *reinterpret_cast<const bf16x8*>(
                &shl[lid * SPITCH + ks2 * 32 + quad * 8]);
            int cg = half * 64 + ks2 * 32;
            #pragma unroll
            for (int mt = 0; mt < 4; ++mt) {
                bf16x8 ah = *reinterpret_cast<const bf16x8*>(
                    wha + (size_t)mt * 16 * C_ + cg);
                bf16x8 al = *reinterpret_cast<const bf16x8*>(
                    wla + (size_t)mt * 16 * C_ + cg);
                acc[mt] = __builtin_amdgcn_mfma_f32_16x16x32_bf16(ah, bh, acc[mt], 0, 0, 0);
                acc[mt] = __builtin_amdgcn_mfma_f32_16x16x32_bf16(al, bh, acc[mt], 0, 0, 0);
                acc[mt] = __builtin_amdgcn_mfma_f32_16x16x32_bf16(ah, bl, acc[mt], 0, 0, 0);
            }
        }
    }
    // reduce sumsq over same-nseg lanes (stride-4 within wave)
    #pragma unroll
    for (int m = 4; m <= 32; m <<= 1) {
        ss0 += __shfl_xor(ss0, m, 64); ss1 += __shfl_xor(ss1, m, 64);
        ss2 += __shfl_xor(ss2, m, 64); ss3 += __shfl_xor(ss3, m, 64);
    }
    if (L < 4) {
        ssq[w][L * 4 + 0] = ss0; ssq[w][L * 4 + 1] = ss1;
        ssq[w][L * 4 + 2] = ss2; ssq[w][L * 4 + 3] = ss3;
    }
    __syncthreads();   // all waves done with stage -> reuse as red
    {
        float* rp = red + w * (16 * 68);
        #pragma unroll
        for (int mt = 0; mt < 4; ++mt)
            *reinterpret_cast<f32x4*>(&rp[lid * 68 + mt * 16 + quad * 4]) = acc[mt];
    }
    __syncthreads();

    // ---- softmax: wave w handles n rows w*4..w*4+3; lane L = k (lockstep rows)
    float vv[4], iv[4];
    #pragma unroll
    for (int i = 0; i < 4; ++i) {
        int n = w * 4 + i;
        float s = ssq[0][n] + ssq[1][n] + ssq[2][n] + ssq[3][n];
        iv[i] = 1.0f / fmaxf(sqrtf(s), EPSV);
        float v = red[0 * 1088 + n * 68 + L] + red[1 * 1088 + n * 68 + L]
                + red[2 * 1088 + n * 68 + L] + red[3 * 1088 + n * 68 + L];
        vv[i] = fmaf(v, iv[i], bk);
    }
    float mx[4] = {vv[0], vv[1], vv[2], vv[3]};
    #pragma unroll
    for (int m = 1; m <= 32; m <<= 1) {
        #pragma unroll
        for (int i = 0; i < 4; ++i) mx[i] = fmaxf(mx[i], __shfl_xor(mx[i], m, 64));
    }
    float e[4], se[4];
    #pragma unroll
    for (int i = 0; i < 4; ++i) { e[i] = __expf(vv[i] - mx[i]); se[i] = e[i]; }
    #pragma unroll
    for (int m = 1; m <= 32; m <<= 1) {
        #pragma unroll
        for (int i = 0; i < 4; ++i) se[i] += __shfl_xor(se[i], m, 64);
    }
    float asl = 0.f;
    unsigned short av[4];
    #pragma unroll
    for (int i = 0; i < 4; ++i) {
        float a = e[i] / se[i];
        av[i] = f2bf(a * iv[i]);
        asl += a;
    }
    atomicAdd(&asum[t * 64 + L], asl);
    ushort4 st; st.x = av[0]; st.y = av[1]; st.z = av[2]; st.w = av[3];
    *reinterpret_cast<ushort4*>(aT + ((size_t)t * 64 + L) * NA_ + n0 + w * 4) = st;
    // fused tail-zero (n=784..800) replaces the aT memset
    if (blockIdx.x == 48) {
        ushort4 z; z.x = 0; z.y = 0; z.z = 0; z.w = 0;
        *reinterpret_cast<ushort4*>(aT + ((size_t)t * 64 + L) * NA_ + 784 + w * 4) = z;
    }
}

// vlad[t][k][c] += sum_{n in half} ahat[k][n]*x[c][n] - (nh==0)*asum[k]*cent[k][c]
// v3: n-reduction split over 2 blocks (grid 32 x 2 x 30 = 1920 blocks, 7.5/CU),
// halves atomicAdd f32 into zeroed vlad. g2 moved to k_g2.
__global__ __launch_bounds__(256, 6) void k_vlad(
    const float* __restrict__ x, const unsigned short* __restrict__ aT,
    const float* __restrict__ asum, const float* __restrict__ cent,
    float* __restrict__ vlad)
{
    __shared__ float red[4][16 * 68];
    int t = blockIdx.z, nh = blockIdx.y, c0 = blockIdx.x * 16;
    int tid = threadIdx.x;
    int w = tid >> 6, L = tid & 63, lid = L & 15, quad = L >> 4;

    f32x4 acc[4];
    #pragma unroll
    for (int mt = 0; mt < 4; ++mt)
        #pragma unroll
        for (int r = 0; r < 4; ++r) acc[mt][r] = 0.f;

    const float* xrow = x + ((size_t)t * C_ + c0 + lid) * N_;
    const unsigned short* a0 = aT + (size_t)t * 64 * NA_ + (size_t)lid * NA_;

    // epilogue operands issued early
    int k = tid >> 2, cs4 = (tid & 3) * 4;
    float as = nh ? 0.f : asum[t * 64 + k];
    float4 cv = *reinterpret_cast<const float4*>(cent + k * C_ + c0 + cs4);

    int send = nh ? 25 : 13;
    int s0 = nh * 13 + w;

    // prologue: load step s0
    int nb = s0 * 32 + quad * 8;
    int nc = nb > 776 ? 776 : nb;   // clamped lanes hit aT zeros
    float4 x0c = *reinterpret_cast<const float4*>(xrow + nc);
    float4 x1c = *reinterpret_cast<const float4*>(xrow + nc + 4);
    bf16x8 f0 = *reinterpret_cast<const bf16x8*>(a0 + nb);
    bf16x8 f1 = *reinterpret_cast<const bf16x8*>(a0 + 16 * NA_ + nb);
    bf16x8 f2 = *reinterpret_cast<const bf16x8*>(a0 + 32 * NA_ + nb);
    bf16x8 f3 = *reinterpret_cast<const bf16x8*>(a0 + 48 * NA_ + nb);

    for (int s = s0; s < send; s += 4) {
        int sn = s + 4;
        float4 x0n = x0c, x1n = x1c;
        bf16x8 g0 = f0, g1 = f1, g2v = f2, g3 = f3;
        if (sn < send) {  // wave-uniform: prefetch next step
            int nb2 = sn * 32 + quad * 8;
            int nc2 = nb2 > 776 ? 776 : nb2;
            x0n = *reinterpret_cast<const float4*>(xrow + nc2);
            x1n = *reinterpret_cast<const float4*>(xrow + nc2 + 4);
            g0 = *reinterpret_cast<const bf16x8*>(a0 + nb2);
            g1 = *reinterpret_cast<const bf16x8*>(a0 + 16 * NA_ + nb2);
            g2v = *reinterpret_cast<const bf16x8*>(a0 + 32 * NA_ + nb2);
            g3 = *reinterpret_cast<const bf16x8*>(a0 + 48 * NA_ + nb2);
        }
        bf16x8 bb;
        bb[0] = (short)f2bf(x0c.x); bb[1] = (short)f2bf(x0c.y);
        bb[2] = (short)f2bf(x0c.z); bb[3] = (short)f2bf(x0c.w);
        bb[4] = (short)f2bf(x1c.x); bb[5] = (short)f2bf(x1c.y);
        bb[6] = (short)f2bf(x1c.z); bb[7] = (short)f2bf(x1c.w);
        acc[0] = __builtin_amdgcn_mfma_f32_16x16x32_bf16(f0, bb, acc[0], 0, 0, 0);
        acc[1] = __builtin_amdgcn_mfma_f32_16x16x32_bf16(f1, bb, acc[1], 0, 0, 0);
        acc[2] = __builtin_amdgcn_mfma_f32_16x16x32_bf16(f2, bb, acc[2], 0, 0, 0);
        acc[3] = __builtin_amdgcn_mfma_f32_16x16x32_bf16(f3, bb, acc[3], 0, 0, 0);
        x0c = x0n; x1c = x1n; f0 = g0; f1 = g1; f2 = g2v; f3 = g3;
    }
    {
        float* rp = &red[w][0];
        #pragma unroll
        for (int mt = 0; mt < 4; ++mt)
            *reinterpret_cast<f32x4*>(&rp[lid * 68 + mt * 16 + quad * 4]) = acc[mt];
    }
    __syncthreads();

    // epilogue: thread -> k = tid>>2, 4 c; atomic combine of the two n-halves
    float* dst = vlad + ((size_t)t * 64 + k) * C_ + c0 + cs4;
    #pragma unroll
    for (int j = 0; j < 4; ++j) {
        int cc = cs4 + j;
        float v = red[0][cc * 68 + k] + red[1][cc * 68 + k]
                + red[2][cc * 68 + k] + red[3][cc * 68 + k];
        v -= as * ((const float*)&cv)[j];
        atomicAdd(dst + j, v);
    }
}

// g2[t][k] = sum_c vlad[t][k][c]^2   (after both n-halves landed)
__global__ __launch_bounds__(256) void k_g2(const float* __restrict__ vlad,
                                            float* __restrict__ g2) {
    int tid = threadIdx.x;
    int w = tid >> 6, L = tid & 63;
    int r = blockIdx.x * 4 + w;          // t*64+k, 0..1919
    const float* p = vlad + (size_t)r * C_;
    float s = 0.f;
    #pragma unroll
    for (int i = 0; i < 2; ++i) {
        float4 a = *reinterpret_cast<const float4*>(p + i * 256 + L * 4);
        s = fmaf(a.x, a.x, fmaf(a.y, a.y, fmaf(a.z, a.z, fmaf(a.w, a.w, s))));
    }
    #pragma unroll
    for (int m = 1; m <= 32; m <<= 1) s += __shfl_xor(s, m, 64);
    if (L == 0) g2[r] = s;
}

// out[k*512+c] = sum_t vlad * inv_intra * inv_g. v3: t split over 2 thread-halves
// (grid 256 blocks, 128 idx each) for 2x parallelism + half-depth load chains.
__global__ __launch_bounds__(256) void k_out(
    const float* __restrict__ vlad, const float* __restrict__ g2,
    float* __restrict__ out)
{
    __shared__ float intr[1920];
    __shared__ float gl[1920];
    __shared__ float sinv[T_];
    __shared__ float part[256];
    int tid = threadIdx.x;
    for (int i = tid; i < 1920; i += 256) {
        float s = g2[i];
        gl[i] = s;
        intr[i] = 1.0f / fmaxf(sqrtf(s), EPSV);
    }
    __syncthreads();
    if (tid < T_) {
        float s = 0.f;
        #pragma unroll 8
        for (int k = 0; k < 64; ++k) {
            float iv = intr[tid * 64 + k];
            s += gl[tid * 64 + k] * iv * iv;
        }
        sinv[tid] = 1.0f / fmaxf(sqrtf(s), EPSV);
    }
    __syncthreads();
    int idx = blockIdx.x * 128 + (tid & 127);  // k*512+c
    int th = tid >> 7;
    int k = idx >> 9;
    float s = 0.f;
    #pragma unroll
    for (int t = th * 15; t < th * 15 + 15; ++t)
        s += vlad[(size_t)t * 32768 + idx] * intr[t * 64 + k] * sinv[t];
    part[tid] = s;
    __syncthreads();
    if (tid < 128) out[idx] = part[tid] + part[tid + 128];
}

extern "C" void kernel_launch(void* const* d_in, const int* in_sizes, int n_in,
                              void* d_out, int out_size, void* d_ws, size_t ws_size,
                              hipStream_t stream) {
    const float* x    = (const float*)d_in[0];   // 30*512*784
    const float* cent = (const float*)d_in[1];   // 64*512
    const float* w    = (const float*)d_in[2];   // 64*512
    const float* b    = (const float*)d_in[3];   // 64
    float* out = (float*)d_out;

    char* p = (char*)d_ws;
    unsigned short* wh = (unsigned short*)p;  p += 65536;
    unsigned short* wl = (unsigned short*)p;  p += 65536;
    float* asum = (float*)p;                  p += 1920 * 4;
    float* vlad = (float*)p;                  p += (size_t)T_ * 64 * C_ * 4;   // 3,932,160
    float* g2   = (float*)p;                  p += 1920 * 4;
    unsigned short* aT = (unsigned short*)p;  p += (size_t)T_ * 64 * NA_ * 2;  // 3,072,000
    // total ~= 7.2 MB

    k_prep<<<128, 256, 0, stream>>>(w, wh, wl);
    hipMemsetAsync(asum, 0, 1920 * 4 + (size_t)T_ * 64 * C_ * 4, stream);  // asum + vlad
    k_assign<<<dim3(49, T_), 256, 0, stream>>>(x, wh, wl, b, aT, asum);
    k_vlad<<<dim3(32, 2, T_), 256, 0, stream>>>(x, aT, asum, cent, vlad);
    k_g2<<<480, 256, 0, stream>>>(vlad, g2);
    k_out<<<256, 256, 0, stream>>>(vlad, g2, out);
}

// Round 4
// 158.063 us; speedup vs baseline: 1.1571x; 1.1571x over previous
//
#include <hip/hip_runtime.h>
#include <math.h>

#define T_ 30
#define C_ 512
#define N_ 784      // 28*28 = 49 tiles of 16
#define NA_ 800     // aT row pitch (25 ksteps of 32)
#define SPITCH 72   // per-wave stage row pitch (ushorts) for one 64-c half
#define EPSV 1e-12f

typedef __attribute__((ext_vector_type(8))) short bf16x8;
typedef __attribute__((ext_vector_type(4))) float f32x4;

__device__ __forceinline__ unsigned short f2bf(float f) {
    union { float f; unsigned int u; } v; v.f = f;
    unsigned int r = (v.u + 0x7FFFu + ((v.u >> 16) & 1u)) >> 16;  // RNE
    return (unsigned short)r;
}
__device__ __forceinline__ float bf2f(unsigned short h) {
    union { unsigned int u; float f; } v; v.u = ((unsigned int)h) << 16;
    return v.f;
}

// wh/wl: split-precision bf16 of w, layout [k][c]
__global__ void k_prep(const float* __restrict__ w, unsigned short* __restrict__ wh,
                       unsigned short* __restrict__ wl) {
    int idx = blockIdx.x * 256 + threadIdx.x;  // 0..32767
    float v = w[idx];
    unsigned short h = f2bf(v);
    wh[idx] = h;
    wl[idx] = f2bf(v - bf2f(h));
}

// Fused invnorm + logits (3-product split-bf16 MFMA) + softmax + aT + asum.
// grid (49, 30), 256 thr. Block: 16 n x 64 k, c-reduction split over 4 waves.
// v4: half-c staging (LDS 18.9 KB => LDS permits 8 blocks/CU) + UNPINNED regs
// (launch_bounds(256,4): R3's (256,8) pin spilled -> 60 MB scratch writes).
__global__ __launch_bounds__(256, 4) void k_assign(
    const float* __restrict__ x, const unsigned short* __restrict__ wh,
    const unsigned short* __restrict__ wl, const float* __restrict__ b,
    unsigned short* __restrict__ aT, float* __restrict__ asum)
{
    // stage: xh/xl [4 w][16 n][SPITCH] ushort (one 64-c half per wave at a time)
    // red (union, reused after MFMA): [4 w][16 n][68 k] f32 = 17408 B
    __shared__ __align__(16) char smem[2 * 4 * 16 * SPITCH * 2];  // 18432 B
    unsigned short* xh = (unsigned short*)smem;
    unsigned short* xl = xh + 4 * 16 * SPITCH;
    float* red = (float*)smem;
    __shared__ float ssq[4][16];

    int t = blockIdx.y, n0 = blockIdx.x * 16;
    int tid = threadIdx.x;
    int w = tid >> 6, L = tid & 63, lid = L & 15, quad = L >> 4;
    int cbase = w * 128;            // wave-private c-slice [cbase, cbase+128)
    int nseg = (L & 3) * 4;         // n offset 0/4/8/12
    int crow = L >> 2;              // 0..15

    const float* xb = x + (size_t)t * C_ * N_ + n0 + nseg;
    unsigned short* shh = xh + w * 16 * SPITCH;
    unsigned short* shl = xl + w * 16 * SPITCH;
    const unsigned short* wha = wh + (size_t)lid * C_ + cbase + quad * 8;
    const unsigned short* wla = wl + (size_t)lid * C_ + cbase + quad * 8;

    float bk = b[L];
    float ss0 = 0.f, ss1 = 0.f, ss2 = 0.f, ss3 = 0.f;
    f32x4 acc[4];
    #pragma unroll
    for (int mt = 0; mt < 4; ++mt)
        #pragma unroll
        for (int r = 0; r < 4; ++r) acc[mt][r] = 0.f;

    #pragma unroll
    for (int half = 0; half < 2; ++half) {
        // load this half's 4 rows per thread (batched, in flight together)
        float4 q[4];
        #pragma unroll
        for (int p = 0; p < 4; ++p)
            q[p] = *reinterpret_cast<const float4*>(
                xb + (size_t)(cbase + half * 64 + p * 16 + crow) * N_);
        // stage (transpose + hi/lo split), accumulate sumsq
        #pragma unroll
        for (int p = 0; p < 4; ++p) {
            int cl = p * 16 + crow;
            float vv[4] = {q[p].x, q[p].y, q[p].z, q[p].w};
            ss0 = fmaf(vv[0], vv[0], ss0); ss1 = fmaf(vv[1], vv[1], ss1);
            ss2 = fmaf(vv[2], vv[2], ss2); ss3 = fmaf(vv[3], vv[3], ss3);
            #pragma unroll
            for (int j = 0; j < 4; ++j) {
                unsigned short h = f2bf(vv[j]);
                shh[(nseg + j) * SPITCH + cl] = h;
                shl[(nseg + j) * SPITCH + cl] = f2bf(vv[j] - bf2f(h));
            }
        }
        // MFMA over this half (reads only this wave's own stage rows)
        #pragma unroll
        for (int ks2 = 0; ks2 < 2; ++ks2) {
            bf16x8 bh = *reinterpret_cast<const bf16x8*>(
                &shh[lid * SPITCH + ks2 * 32 + quad * 8]);
            bf16x8 bl = *reinterpret_cast<const bf16x8*>(
                &shl[lid * SPITCH + ks2 * 32 + quad * 8]);
            int cg = half * 64 + ks2 * 32;
            #pragma unroll
            for (int mt = 0; mt < 4; ++mt) {
                bf16x8 ah = *reinterpret_cast<const bf16x8*>(
                    wha + (size_t)mt * 16 * C_ + cg);
                bf16x8 al = *reinterpret_cast<const bf16x8*>(
                    wla + (size_t)mt * 16 * C_ + cg);
                acc[mt] = __builtin_amdgcn_mfma_f32_16x16x32_bf16(ah, bh, acc[mt], 0, 0, 0);
                acc[mt] = __builtin_amdgcn_mfma_f32_16x16x32_bf16(al, bh, acc[mt], 0, 0, 0);
                acc[mt] = __builtin_amdgcn_mfma_f32_16x16x32_bf16(ah, bl, acc[mt], 0, 0, 0);
            }
        }
    }
    // reduce sumsq over same-nseg lanes (stride-4 within wave)
    #pragma unroll
    for (int m = 4; m <= 32; m <<= 1) {
        ss0 += __shfl_xor(ss0, m, 64); ss1 += __shfl_xor(ss1, m, 64);
        ss2 += __shfl_xor(ss2, m, 64); ss3 += __shfl_xor(ss3, m, 64);
    }
    if (L < 4) {
        ssq[w][L * 4 + 0] = ss0; ssq[w][L * 4 + 1] = ss1;
        ssq[w][L * 4 + 2] = ss2; ssq[w][L * 4 + 3] = ss3;
    }
    __syncthreads();   // all waves done with stage -> reuse as red
    {
        float* rp = red + w * (16 * 68);
        #pragma unroll
        for (int mt = 0; mt < 4; ++mt)
            *reinterpret_cast<f32x4*>(&rp[lid * 68 + mt * 16 + quad * 4]) = acc[mt];
    }
    __syncthreads();

    // ---- softmax: wave w handles n rows w*4..w*4+3; lane L = k (lockstep rows)
    float vv[4], iv[4];
    #pragma unroll
    for (int i = 0; i < 4; ++i) {
        int n = w * 4 + i;
        float s = ssq[0][n] + ssq[1][n] + ssq[2][n] + ssq[3][n];
        iv[i] = 1.0f / fmaxf(sqrtf(s), EPSV);
        float v = red[0 * 1088 + n * 68 + L] + red[1 * 1088 + n * 68 + L]
                + red[2 * 1088 + n * 68 + L] + red[3 * 1088 + n * 68 + L];
        vv[i] = fmaf(v, iv[i], bk);
    }
    float mx[4] = {vv[0], vv[1], vv[2], vv[3]};
    #pragma unroll
    for (int m = 1; m <= 32; m <<= 1) {
        #pragma unroll
        for (int i = 0; i < 4; ++i) mx[i] = fmaxf(mx[i], __shfl_xor(mx[i], m, 64));
    }
    float e[4], se[4];
    #pragma unroll
    for (int i = 0; i < 4; ++i) { e[i] = __expf(vv[i] - mx[i]); se[i] = e[i]; }
    #pragma unroll
    for (int m = 1; m <= 32; m <<= 1) {
        #pragma unroll
        for (int i = 0; i < 4; ++i) se[i] += __shfl_xor(se[i], m, 64);
    }
    float asl = 0.f;
    unsigned short av[4];
    #pragma unroll
    for (int i = 0; i < 4; ++i) {
        float a = e[i] / se[i];
        av[i] = f2bf(a * iv[i]);
        asl += a;
    }
    atomicAdd(&asum[t * 64 + L], asl);
    ushort4 st; st.x = av[0]; st.y = av[1]; st.z = av[2]; st.w = av[3];
    *reinterpret_cast<ushort4*>(aT + ((size_t)t * 64 + L) * NA_ + n0 + w * 4) = st;
    // fused tail-zero (n=784..800) replaces the aT memset
    if (blockIdx.x == 48) {
        ushort4 z; z.x = 0; z.y = 0; z.z = 0; z.w = 0;
        *reinterpret_cast<ushort4*>(aT + ((size_t)t * 64 + L) * NA_ + 784 + w * 4) = z;
    }
}

// vlad[t][k][c] += sum_{n in half} ahat[k][n]*x[c][n] - (nh==0)*asum[k]*cent[k][c]
// grid 32 x 2 x 30 = 1920 blocks (7.5/CU); halves atomicAdd into zeroed vlad.
// v4: pin released ((256,4), 128-VGPR budget) -- R3's (256,6) spilled.
__global__ __launch_bounds__(256, 4) void k_vlad(
    const float* __restrict__ x, const unsigned short* __restrict__ aT,
    const float* __restrict__ asum, const float* __restrict__ cent,
    float* __restrict__ vlad)
{
    __shared__ float red[4][16 * 68];
    int t = blockIdx.z, nh = blockIdx.y, c0 = blockIdx.x * 16;
    int tid = threadIdx.x;
    int w = tid >> 6, L = tid & 63, lid = L & 15, quad = L >> 4;

    f32x4 acc[4];
    #pragma unroll
    for (int mt = 0; mt < 4; ++mt)
        #pragma unroll
        for (int r = 0; r < 4; ++r) acc[mt][r] = 0.f;

    const float* xrow = x + ((size_t)t * C_ + c0 + lid) * N_;
    const unsigned short* a0 = aT + (size_t)t * 64 * NA_ + (size_t)lid * NA_;

    // epilogue operands issued early
    int k = tid >> 2, cs4 = (tid & 3) * 4;
    float as = nh ? 0.f : asum[t * 64 + k];
    float4 cv = *reinterpret_cast<const float4*>(cent + k * C_ + c0 + cs4);

    int send = nh ? 25 : 13;
    int s0 = nh * 13 + w;

    // prologue: load step s0
    int nb = s0 * 32 + quad * 8;
    int nc = nb > 776 ? 776 : nb;   // clamped lanes hit aT zeros
    float4 x0c = *reinterpret_cast<const float4*>(xrow + nc);
    float4 x1c = *reinterpret_cast<const float4*>(xrow + nc + 4);
    bf16x8 f0 = *reinterpret_cast<const bf16x8*>(a0 + nb);
    bf16x8 f1 = *reinterpret_cast<const bf16x8*>(a0 + 16 * NA_ + nb);
    bf16x8 f2 = *reinterpret_cast<const bf16x8*>(a0 + 32 * NA_ + nb);
    bf16x8 f3 = *reinterpret_cast<const bf16x8*>(a0 + 48 * NA_ + nb);

    for (int s = s0; s < send; s += 4) {
        int sn = s + 4;
        float4 x0n = x0c, x1n = x1c;
        bf16x8 g0 = f0, g1 = f1, g2v = f2, g3 = f3;
        if (sn < send) {  // wave-uniform: prefetch next step
            int nb2 = sn * 32 + quad * 8;
            int nc2 = nb2 > 776 ? 776 : nb2;
            x0n = *reinterpret_cast<const float4*>(xrow + nc2);
            x1n = *reinterpret_cast<const float4*>(xrow + nc2 + 4);
            g0 = *reinterpret_cast<const bf16x8*>(a0 + nb2);
            g1 = *reinterpret_cast<const bf16x8*>(a0 + 16 * NA_ + nb2);
            g2v = *reinterpret_cast<const bf16x8*>(a0 + 32 * NA_ + nb2);
            g3 = *reinterpret_cast<const bf16x8*>(a0 + 48 * NA_ + nb2);
        }
        bf16x8 bb;
        bb[0] = (short)f2bf(x0c.x); bb[1] = (short)f2bf(x0c.y);
        bb[2] = (short)f2bf(x0c.z); bb[3] = (short)f2bf(x0c.w);
        bb[4] = (short)f2bf(x1c.x); bb[5] = (short)f2bf(x1c.y);
        bb[6] = (short)f2bf(x1c.z); bb[7] = (short)f2bf(x1c.w);
        acc[0] = __builtin_amdgcn_mfma_f32_16x16x32_bf16(f0, bb, acc[0], 0, 0, 0);
        acc[1] = __builtin_amdgcn_mfma_f32_16x16x32_bf16(f1, bb, acc[1], 0, 0, 0);
        acc[2] = __builtin_amdgcn_mfma_f32_16x16x32_bf16(f2, bb, acc[2], 0, 0, 0);
        acc[3] = __builtin_amdgcn_mfma_f32_16x16x32_bf16(f3, bb, acc[3], 0, 0, 0);
        x0c = x0n; x1c = x1n; f0 = g0; f1 = g1; f2 = g2v; f3 = g3;
    }
    {
        float* rp = &red[w][0];
        #pragma unroll
        for (int mt = 0; mt < 4; ++mt)
            *reinterpret_cast<f32x4*>(&rp[lid * 68 + mt * 16 + quad * 4]) = acc[mt];
    }
    __syncthreads();

    // epilogue: thread -> k = tid>>2, 4 c; atomic combine of the two n-halves
    float* dst = vlad + ((size_t)t * 64 + k) * C_ + c0 + cs4;
    #pragma unroll
    for (int j = 0; j < 4; ++j) {
        int cc = cs4 + j;
        float v = red[0][cc * 68 + k] + red[1][cc * 68 + k]
                + red[2][cc * 68 + k] + red[3][cc * 68 + k];
        v -= as * ((const float*)&cv)[j];
        atomicAdd(dst + j, v);
    }
}

// g2[t][k] = sum_c vlad[t][k][c]^2   (after both n-halves landed)
__global__ __launch_bounds__(256) void k_g2(const float* __restrict__ vlad,
                                            float* __restrict__ g2) {
    int tid = threadIdx.x;
    int w = tid >> 6, L = tid & 63;
    int r = blockIdx.x * 4 + w;          // t*64+k, 0..1919
    const float* p = vlad + (size_t)r * C_;
    float s = 0.f;
    #pragma unroll
    for (int i = 0; i < 2; ++i) {
        float4 a = *reinterpret_cast<const float4*>(p + i * 256 + L * 4);
        s = fmaf(a.x, a.x, fmaf(a.y, a.y, fmaf(a.z, a.z, fmaf(a.w, a.w, s))));
    }
    #pragma unroll
    for (int m = 1; m <= 32; m <<= 1) s += __shfl_xor(s, m, 64);
    if (L == 0) g2[r] = s;
}

// out[k*512+c] = sum_t vlad * inv_intra * inv_g. t split over 2 thread-halves
// (grid 256 blocks, 128 idx each) for 2x parallelism + half-depth load chains.
__global__ __launch_bounds__(256) void k_out(
    const float* __restrict__ vlad, const float* __restrict__ g2,
    float* __restrict__ out)
{
    __shared__ float intr[1920];
    __shared__ float gl[1920];
    __shared__ float sinv[T_];
    __shared__ float part[256];
    int tid = threadIdx.x;
    for (int i = tid; i < 1920; i += 256) {
        float s = g2[i];
        gl[i] = s;
        intr[i] = 1.0f / fmaxf(sqrtf(s), EPSV);
    }
    __syncthreads();
    if (tid < T_) {
        float s = 0.f;
        #pragma unroll 8
        for (int k = 0; k < 64; ++k) {
            float iv = intr[tid * 64 + k];
            s += gl[tid * 64 + k] * iv * iv;
        }
        sinv[tid] = 1.0f / fmaxf(sqrtf(s), EPSV);
    }
    __syncthreads();
    int idx = blockIdx.x * 128 + (tid & 127);  // k*512+c
    int th = tid >> 7;
    int k = idx >> 9;
    float s = 0.f;
    #pragma unroll
    for (int t = th * 15; t < th * 15 + 15; ++t)
        s += vlad[(size_t)t * 32768 + idx] * intr[t * 64 + k] * sinv[t];
    part[tid] = s;
    __syncthreads();
    if (tid < 128) out[idx] = part[tid] + part[tid + 128];
}

extern "C" void kernel_launch(void* const* d_in, const int* in_sizes, int n_in,
                              void* d_out, int out_size, void* d_ws, size_t ws_size,
                              hipStream_t stream) {
    const float* x    = (const float*)d_in[0];   // 30*512*784
    const float* cent = (const float*)d_in[1];   // 64*512
    const float* w    = (const float*)d_in[2];   // 64*512
    const float* b    = (const float*)d_in[3];   // 64
    float* out = (float*)d_out;

    char* p = (char*)d_ws;
    unsigned short* wh = (unsigned short*)p;  p += 65536;
    unsigned short* wl = (unsigned short*)p;  p += 65536;
    float* asum = (float*)p;                  p += 1920 * 4;
    float* vlad = (float*)p;                  p += (size_t)T_ * 64 * C_ * 4;   // 3,932,160
    float* g2   = (float*)p;                  p += 1920 * 4;
    unsigned short* aT = (unsigned short*)p;  p += (size_t)T_ * 64 * NA_ * 2;  // 3,072,000
    // total ~= 7.2 MB

    k_prep<<<128, 256, 0, stream>>>(w, wh, wl);
    hipMemsetAsync(asum, 0, 1920 * 4 + (size_t)T_ * 64 * C_ * 4, stream);  // asum + vlad
    k_assign<<<dim3(49, T_), 256, 0, stream>>>(x, wh, wl, b, aT, asum);
    k_vlad<<<dim3(32, 2, T_), 256, 0, stream>>>(x, aT, asum, cent, vlad);
    k_g2<<<480, 256, 0, stream>>>(vlad, g2);
    k_out<<<256, 256, 0, stream>>>(vlad, g2, out);
}

// Round 5
// 148.047 us; speedup vs baseline: 1.2353x; 1.0677x over previous
//
#include <hip/hip_runtime.h>
#include <math.h>

#define T_ 30
#define C_ 512
#define N_ 784      // 28*28 = 49 tiles of 16
#define NA_ 800     // aT row pitch (25 ksteps of 32)
#define XBP 800     // xbh row pitch in ushorts (zero tail 784..800)
#define SPITCH 72   // per-wave stage row pitch (ushorts) for one 64-c half
#define EPSV 1e-12f

typedef __attribute__((ext_vector_type(8))) short bf16x8;
typedef __attribute__((ext_vector_type(4))) float f32x4;

__device__ __forceinline__ unsigned short f2bf(float f) {
    union { float f; unsigned int u; } v; v.f = f;
    unsigned int r = (v.u + 0x7FFFu + ((v.u >> 16) & 1u)) >> 16;  // RNE
    return (unsigned short)r;
}
__device__ __forceinline__ float bf2f(unsigned short h) {
    union { unsigned int u; float f; } v; v.u = ((unsigned int)h) << 16;
    return v.f;
}

// wh/wl: split-precision bf16 of w, layout [k][c]
__global__ void k_prep(const float* __restrict__ w, unsigned short* __restrict__ wh,
                       unsigned short* __restrict__ wl) {
    int idx = blockIdx.x * 256 + threadIdx.x;  // 0..32767
    float v = w[idx];
    unsigned short h = f2bf(v);
    wh[idx] = h;
    wl[idx] = f2bf(v - bf2f(h));
}

// Fused invnorm + logits (3-product split-bf16 MFMA) + softmax + aT + asum.
// grid (49, 30), 256 thr. Block: 16 n x 64 k, c-reduction split over 4 waves.
// v5: 8-deep x-load batch (R1-proven <=64 VGPR), exports hi-bf16 of x to xbh
// for k_vlad (halves its read traffic), fused zero-tails for aT and xbh.
__global__ __launch_bounds__(256, 4) void k_assign(
    const float* __restrict__ x, const unsigned short* __restrict__ wh,
    const unsigned short* __restrict__ wl, const float* __restrict__ b,
    unsigned short* __restrict__ aT, float* __restrict__ asum,
    unsigned short* __restrict__ xbh)
{
    // stage: xh/xl [4 w][16 n][SPITCH] ushort (one 64-c half per wave at a time)
    // red (union, reused after MFMA): [4 w][16 n][68 k] f32 = 17408 B
    __shared__ __align__(16) char smem[2 * 4 * 16 * SPITCH * 2];  // 18432 B
    unsigned short* xh = (unsigned short*)smem;
    unsigned short* xl = xh + 4 * 16 * SPITCH;
    float* red = (float*)smem;
    __shared__ float ssq[4][16];

    int t = blockIdx.y, n0 = blockIdx.x * 16;
    int tid = threadIdx.x;
    int w = tid >> 6, L = tid & 63, lid = L & 15, quad = L >> 4;
    int cbase = w * 128;            // wave-private c-slice [cbase, cbase+128)
    int nseg = (L & 3) * 4;         // n offset 0/4/8/12
    int crow = L >> 2;              // 0..15

    const float* xb = x + (size_t)t * C_ * N_ + n0 + nseg;
    unsigned short* xbrow = xbh + (size_t)t * C_ * XBP + n0 + nseg;
    unsigned short* shh = xh + w * 16 * SPITCH;
    unsigned short* shl = xl + w * 16 * SPITCH;
    const unsigned short* wha = wh + (size_t)lid * C_ + cbase + quad * 8;
    const unsigned short* wla = wl + (size_t)lid * C_ + cbase + quad * 8;

    // all 8 x loads in flight together (the long-pole HBM latency)
    float4 q[8];
    #pragma unroll
    for (int p = 0; p < 8; ++p)
        q[p] = *reinterpret_cast<const float4*>(
            xb + (size_t)(cbase + p * 16 + crow) * N_);

    float bk = b[L];
    float ss0 = 0.f, ss1 = 0.f, ss2 = 0.f, ss3 = 0.f;
    f32x4 acc[4];
    #pragma unroll
    for (int mt = 0; mt < 4; ++mt)
        #pragma unroll
        for (int r = 0; r < 4; ++r) acc[mt][r] = 0.f;

    #pragma unroll
    for (int half = 0; half < 2; ++half) {
        // stage (transpose + hi/lo split), accumulate sumsq, export hi-bf16
        #pragma unroll
        for (int p = 0; p < 4; ++p) {
            int pp = half * 4 + p;
            int cl = p * 16 + crow;            // 0..63 within stage
            int c  = cbase + pp * 16 + crow;   // global c
            float vv[4] = {q[pp].x, q[pp].y, q[pp].z, q[pp].w};
            ss0 = fmaf(vv[0], vv[0], ss0); ss1 = fmaf(vv[1], vv[1], ss1);
            ss2 = fmaf(vv[2], vv[2], ss2); ss3 = fmaf(vv[3], vv[3], ss3);
            unsigned short hs[4];
            #pragma unroll
            for (int j = 0; j < 4; ++j) {
                unsigned short h = f2bf(vv[j]);
                hs[j] = h;
                shh[(nseg + j) * SPITCH + cl] = h;
                shl[(nseg + j) * SPITCH + cl] = f2bf(vv[j] - bf2f(h));
            }
            ushort4 hv; hv.x = hs[0]; hv.y = hs[1]; hv.z = hs[2]; hv.w = hs[3];
            *reinterpret_cast<ushort4*>(xbrow + (size_t)c * XBP) = hv;
        }
        // MFMA over this half (reads only this wave's own stage rows)
        #pragma unroll
        for (int ks2 = 0; ks2 < 2; ++ks2) {
            bf16x8 bh = *reinterpret_cast<const bf16x8*>(
                &shh[lid * SPITCH + ks2 * 32 + quad * 8]);
            bf16x8 bl = *reinterpret_cast<const bf16x8*>(
                &shl[lid * SPITCH + ks2 * 32 + quad * 8]);
            int cg = half * 64 + ks2 * 32;
            #pragma unroll
            for (int mt = 0; mt < 4; ++mt) {
                bf16x8 ah = *reinterpret_cast<const bf16x8*>(
                    wha + (size_t)mt * 16 * C_ + cg);
                bf16x8 al = *reinterpret_cast<const bf16x8*>(
                    wla + (size_t)mt * 16 * C_ + cg);
                acc[mt] = __builtin_amdgcn_mfma_f32_16x16x32_bf16(ah, bh, acc[mt], 0, 0, 0);
                acc[mt] = __builtin_amdgcn_mfma_f32_16x16x32_bf16(al, bh, acc[mt], 0, 0, 0);
                acc[mt] = __builtin_amdgcn_mfma_f32_16x16x32_bf16(ah, bl, acc[mt], 0, 0, 0);
            }
        }
    }
    // reduce sumsq over same-nseg lanes (stride-4 within wave)
    #pragma unroll
    for (int m = 4; m <= 32; m <<= 1) {
        ss0 += __shfl_xor(ss0, m, 64); ss1 += __shfl_xor(ss1, m, 64);
        ss2 += __shfl_xor(ss2, m, 64); ss3 += __shfl_xor(ss3, m, 64);
    }
    if (L < 4) {
        ssq[w][L * 4 + 0] = ss0; ssq[w][L * 4 + 1] = ss1;
        ssq[w][L * 4 + 2] = ss2; ssq[w][L * 4 + 3] = ss3;
    }
    __syncthreads();   // all waves done with stage -> reuse as red
    {
        float* rp = red + w * (16 * 68);
        #pragma unroll
        for (int mt = 0; mt < 4; ++mt)
            *reinterpret_cast<f32x4*>(&rp[lid * 68 + mt * 16 + quad * 4]) = acc[mt];
    }
    __syncthreads();

    // ---- softmax: wave w handles n rows w*4..w*4+3; lane L = k (lockstep rows)
    float vv[4], iv[4];
    #pragma unroll
    for (int i = 0; i < 4; ++i) {
        int n = w * 4 + i;
        float s = ssq[0][n] + ssq[1][n] + ssq[2][n] + ssq[3][n];
        iv[i] = 1.0f / fmaxf(sqrtf(s), EPSV);
        float v = red[0 * 1088 + n * 68 + L] + red[1 * 1088 + n * 68 + L]
                + red[2 * 1088 + n * 68 + L] + red[3 * 1088 + n * 68 + L];
        vv[i] = fmaf(v, iv[i], bk);
    }
    float mx[4] = {vv[0], vv[1], vv[2], vv[3]};
    #pragma unroll
    for (int m = 1; m <= 32; m <<= 1) {
        #pragma unroll
        for (int i = 0; i < 4; ++i) mx[i] = fmaxf(mx[i], __shfl_xor(mx[i], m, 64));
    }
    float e[4], se[4];
    #pragma unroll
    for (int i = 0; i < 4; ++i) { e[i] = __expf(vv[i] - mx[i]); se[i] = e[i]; }
    #pragma unroll
    for (int m = 1; m <= 32; m <<= 1) {
        #pragma unroll
        for (int i = 0; i < 4; ++i) se[i] += __shfl_xor(se[i], m, 64);
    }
    float asl = 0.f;
    unsigned short av[4];
    #pragma unroll
    for (int i = 0; i < 4; ++i) {
        float a = e[i] / se[i];
        av[i] = f2bf(a * iv[i]);
        asl += a;
    }
    atomicAdd(&asum[t * 64 + L], asl);
    ushort4 st; st.x = av[0]; st.y = av[1]; st.z = av[2]; st.w = av[3];
    *reinterpret_cast<ushort4*>(aT + ((size_t)t * 64 + L) * NA_ + n0 + w * 4) = st;
    // fused zero-tails (n=784..800) for aT and xbh (replace memsets)
    if (blockIdx.x == 48) {
        ushort4 z; z.x = 0; z.y = 0; z.z = 0; z.w = 0;
        *reinterpret_cast<ushort4*>(aT + ((size_t)t * 64 + L) * NA_ + 784 + w * 4) = z;
        #pragma unroll
        for (int pp = 0; pp < 8; ++pp) {
            int c = cbase + pp * 16 + crow;
            *reinterpret_cast<ushort4*>(
                xbh + ((size_t)t * C_ + c) * XBP + 784 + nseg) = z;
        }
    }
}

// vlad half-partials: nh block computes sum over its n-range; nh=0 also
// subtracts asum*cent. NON-atomic stores into vlad0/vlad1 (no memset needed).
// B operand = precomputed hi-bf16 xbh (bit-identical to f2bf(x), half traffic).
__global__ __launch_bounds__(256, 4) void k_vlad(
    const unsigned short* __restrict__ xbh, const unsigned short* __restrict__ aT,
    const float* __restrict__ asum, const float* __restrict__ cent,
    float* __restrict__ vlad0, float* __restrict__ vlad1)
{
    __shared__ float red[4][16 * 68];
    int t = blockIdx.z, nh = blockIdx.y, c0 = blockIdx.x * 16;
    int tid = threadIdx.x;
    int w = tid >> 6, L = tid & 63, lid = L & 15, quad = L >> 4;

    f32x4 acc[4];
    #pragma unroll
    for (int mt = 0; mt < 4; ++mt)
        #pragma unroll
        for (int r = 0; r < 4; ++r) acc[mt][r] = 0.f;

    const unsigned short* xrow = xbh + ((size_t)t * C_ + c0 + lid) * XBP;
    const unsigned short* a0 = aT + (size_t)t * 64 * NA_ + (size_t)lid * NA_;

    // epilogue operands issued early
    int k = tid >> 2, cs4 = (tid & 3) * 4;
    float as = nh ? 0.f : asum[t * 64 + k];
    float4 cv = *reinterpret_cast<const float4*>(cent + k * C_ + c0 + cs4);

    int send = nh ? 25 : 13;
    int s0 = nh * 13 + w;

    // prologue: load step s0 (tails n=784..800 are zero in both aT and xbh)
    int nb = s0 * 32 + quad * 8;
    bf16x8 xc = *reinterpret_cast<const bf16x8*>(xrow + nb);
    bf16x8 f0 = *reinterpret_cast<const bf16x8*>(a0 + nb);
    bf16x8 f1 = *reinterpret_cast<const bf16x8*>(a0 + 16 * NA_ + nb);
    bf16x8 f2 = *reinterpret_cast<const bf16x8*>(a0 + 32 * NA_ + nb);
    bf16x8 f3 = *reinterpret_cast<const bf16x8*>(a0 + 48 * NA_ + nb);

    for (int s = s0; s < send; s += 4) {
        int sn = s + 4;
        bf16x8 xn = xc;
        bf16x8 g0 = f0, g1 = f1, g2v = f2, g3 = f3;
        if (sn < send) {  // wave-uniform: prefetch next step
            int nb2 = sn * 32 + quad * 8;
            xn  = *reinterpret_cast<const bf16x8*>(xrow + nb2);
            g0  = *reinterpret_cast<const bf16x8*>(a0 + nb2);
            g1  = *reinterpret_cast<const bf16x8*>(a0 + 16 * NA_ + nb2);
            g2v = *reinterpret_cast<const bf16x8*>(a0 + 32 * NA_ + nb2);
            g3  = *reinterpret_cast<const bf16x8*>(a0 + 48 * NA_ + nb2);
        }
        acc[0] = __builtin_amdgcn_mfma_f32_16x16x32_bf16(f0, xc, acc[0], 0, 0, 0);
        acc[1] = __builtin_amdgcn_mfma_f32_16x16x32_bf16(f1, xc, acc[1], 0, 0, 0);
        acc[2] = __builtin_amdgcn_mfma_f32_16x16x32_bf16(f2, xc, acc[2], 0, 0, 0);
        acc[3] = __builtin_amdgcn_mfma_f32_16x16x32_bf16(f3, xc, acc[3], 0, 0, 0);
        xc = xn; f0 = g0; f1 = g1; f2 = g2v; f3 = g3;
    }
    {
        float* rp = &red[w][0];
        #pragma unroll
        for (int mt = 0; mt < 4; ++mt)
            *reinterpret_cast<f32x4*>(&rp[lid * 68 + mt * 16 + quad * 4]) = acc[mt];
    }
    __syncthreads();

    // epilogue: thread -> k = tid>>2, 4 c; plain store to own half-buffer
    float* dst = (nh ? vlad1 : vlad0) + ((size_t)t * 64 + k) * C_ + c0 + cs4;
    float4 vout;
    #pragma unroll
    for (int j = 0; j < 4; ++j) {
        int cc = cs4 + j;
        float v = red[0][cc * 68 + k] + red[1][cc * 68 + k]
                + red[2][cc * 68 + k] + red[3][cc * 68 + k];
        v -= as * ((const float*)&cv)[j];
        ((float*)&vout)[j] = v;
    }
    *reinterpret_cast<float4*>(dst) = vout;
}

// g2[t][k] = sum_c (vlad0+vlad1)^2
__global__ __launch_bounds__(256) void k_g2(const float* __restrict__ vlad0,
                                            const float* __restrict__ vlad1,
                                            float* __restrict__ g2) {
    int tid = threadIdx.x;
    int w = tid >> 6, L = tid & 63;
    int r = blockIdx.x * 4 + w;          // t*64+k, 0..1919
    const float* p0 = vlad0 + (size_t)r * C_;
    const float* p1 = vlad1 + (size_t)r * C_;
    float s = 0.f;
    #pragma unroll
    for (int i = 0; i < 2; ++i) {
        float4 a = *reinterpret_cast<const float4*>(p0 + i * 256 + L * 4);
        float4 b4 = *reinterpret_cast<const float4*>(p1 + i * 256 + L * 4);
        float vx = a.x + b4.x, vy = a.y + b4.y, vz = a.z + b4.z, vw = a.w + b4.w;
        s = fmaf(vx, vx, fmaf(vy, vy, fmaf(vz, vz, fmaf(vw, vw, s))));
    }
    #pragma unroll
    for (int m = 1; m <= 32; m <<= 1) s += __shfl_xor(s, m, 64);
    if (L == 0) g2[r] = s;
}

// out[k*512+c] = sum_t (vlad0+vlad1) * inv_intra * inv_g
__global__ __launch_bounds__(256) void k_out(
    const float* __restrict__ vlad0, const float* __restrict__ vlad1,
    const float* __restrict__ g2, float* __restrict__ out)
{
    __shared__ float intr[1920];
    __shared__ float gl[1920];
    __shared__ float sinv[T_];
    __shared__ float part[256];
    int tid = threadIdx.x;
    for (int i = tid; i < 1920; i += 256) {
        float s = g2[i];
        gl[i] = s;
        intr[i] = 1.0f / fmaxf(sqrtf(s), EPSV);
    }
    __syncthreads();
    if (tid < T_) {
        float s = 0.f;
        #pragma unroll 8
        for (int k = 0; k < 64; ++k) {
            float iv = intr[tid * 64 + k];
            s += gl[tid * 64 + k] * iv * iv;
        }
        sinv[tid] = 1.0f / fmaxf(sqrtf(s), EPSV);
    }
    __syncthreads();
    int idx = blockIdx.x * 128 + (tid & 127);  // k*512+c
    int th = tid >> 7;
    int k = idx >> 9;
    float s = 0.f;
    #pragma unroll
    for (int t = th * 15; t < th * 15 + 15; ++t) {
        size_t off = (size_t)t * 32768 + idx;
        s += (vlad0[off] + vlad1[off]) * intr[t * 64 + k] * sinv[t];
    }
    part[tid] = s;
    __syncthreads();
    if (tid < 128) out[idx] = part[tid] + part[tid + 128];
}

extern "C" void kernel_launch(void* const* d_in, const int* in_sizes, int n_in,
                              void* d_out, int out_size, void* d_ws, size_t ws_size,
                              hipStream_t stream) {
    const float* x    = (const float*)d_in[0];   // 30*512*784
    const float* cent = (const float*)d_in[1];   // 64*512
    const float* w    = (const float*)d_in[2];   // 64*512
    const float* b    = (const float*)d_in[3];   // 64
    float* out = (float*)d_out;

    char* p = (char*)d_ws;
    unsigned short* wh = (unsigned short*)p;   p += 65536;
    unsigned short* wl = (unsigned short*)p;   p += 65536;
    float* asum  = (float*)p;                  p += 1920 * 4;
    float* g2    = (float*)p;                  p += 1920 * 4;
    float* vlad0 = (float*)p;                  p += (size_t)T_ * 64 * C_ * 4;  // 3,932,160
    float* vlad1 = (float*)p;                  p += (size_t)T_ * 64 * C_ * 4;  // 3,932,160
    unsigned short* aT = (unsigned short*)p;   p += (size_t)T_ * 64 * NA_ * 2; // 3,072,000
    unsigned short* xbh = (unsigned short*)p;  p += (size_t)T_ * C_ * XBP * 2; // 24,576,000
    // total ~= 35.7 MB

    k_prep<<<128, 256, 0, stream>>>(w, wh, wl);
    hipMemsetAsync(asum, 0, 1920 * 4, stream);   // only asum (7.7 KB) needs zeroing
    k_assign<<<dim3(49, T_), 256, 0, stream>>>(x, wh, wl, b, aT, asum, xbh);
    k_vlad<<<dim3(32, 2, T_), 256, 0, stream>>>(xbh, aT, asum, cent, vlad0, vlad1);
    k_g2<<<480, 256, 0, stream>>>(vlad0, vlad1, g2);
    k_out<<<256, 256, 0, stream>>>(vlad0, vlad1, g2, out);
}

// Round 6
// 142.106 us; speedup vs baseline: 1.2870x; 1.0418x over previous
//
#include <hip/hip_runtime.h>
#include <math.h>

#define T_ 30
#define C_ 512
#define N_ 784      // 28*28 = 49 tiles of 16
#define NA_ 800     // aT row pitch (25 ksteps of 32)
#define SPITCH 72   // per-wave stage row pitch (ushorts) for one 64-c half
#define EPSV 1e-12f

typedef __attribute__((ext_vector_type(8))) short bf16x8;
typedef __attribute__((ext_vector_type(4))) float f32x4;

__device__ __forceinline__ unsigned short f2bf(float f) {
    union { float f; unsigned int u; } v; v.f = f;
    unsigned int r = (v.u + 0x7FFFu + ((v.u >> 16) & 1u)) >> 16;  // RNE
    return (unsigned short)r;
}
__device__ __forceinline__ float bf2f(unsigned short h) {
    union { unsigned int u; float f; } v; v.u = ((unsigned int)h) << 16;
    return v.f;
}

// wh/wl: split-precision bf16 of w, layout [k][c]
__global__ void k_prep(const float* __restrict__ w, unsigned short* __restrict__ wh,
                       unsigned short* __restrict__ wl) {
    int idx = blockIdx.x * 256 + threadIdx.x;  // 0..32767
    float v = w[idx];
    unsigned short h = f2bf(v);
    wh[idx] = h;
    wl[idx] = f2bf(v - bf2f(h));
}

// Fused invnorm + logits (3-product split-bf16 MFMA) + softmax + aT + asum.
// grid (49, 30), 256 thr. Block: 16 n x 64 k, c-reduction split over 4 waves.
// v6 == v4 (proven 44 us): 8-deep x-load batch, wave-private half-c staging,
// no xbh export (x stays L3-resident for k_vlad; exporting it was a traffic wash).
__global__ __launch_bounds__(256, 4) void k_assign(
    const float* __restrict__ x, const unsigned short* __restrict__ wh,
    const unsigned short* __restrict__ wl, const float* __restrict__ b,
    unsigned short* __restrict__ aT, float* __restrict__ asum)
{
    // stage: xh/xl [4 w][16 n][SPITCH] ushort (one 64-c half per wave at a time)
    // red (union, reused after MFMA): [4 w][16 n][68 k] f32 = 17408 B
    __shared__ __align__(16) char smem[2 * 4 * 16 * SPITCH * 2];  // 18432 B
    unsigned short* xh = (unsigned short*)smem;
    unsigned short* xl = xh + 4 * 16 * SPITCH;
    float* red = (float*)smem;
    __shared__ float ssq[4][16];

    int t = blockIdx.y, n0 = blockIdx.x * 16;
    int tid = threadIdx.x;
    int w = tid >> 6, L = tid & 63, lid = L & 15, quad = L >> 4;
    int cbase = w * 128;            // wave-private c-slice [cbase, cbase+128)
    int nseg = (L & 3) * 4;         // n offset 0/4/8/12
    int crow = L >> 2;              // 0..15

    const float* xb = x + (size_t)t * C_ * N_ + n0 + nseg;
    unsigned short* shh = xh + w * 16 * SPITCH;
    unsigned short* shl = xl + w * 16 * SPITCH;
    const unsigned short* wha = wh + (size_t)lid * C_ + cbase + quad * 8;
    const unsigned short* wla = wl + (size_t)lid * C_ + cbase + quad * 8;

    // all 8 x loads in flight together (the long-pole HBM latency)
    float4 q[8];
    #pragma unroll
    for (int p = 0; p < 8; ++p)
        q[p] = *reinterpret_cast<const float4*>(
            xb + (size_t)(cbase + p * 16 + crow) * N_);

    float bk = b[L];
    float ss0 = 0.f, ss1 = 0.f, ss2 = 0.f, ss3 = 0.f;
    f32x4 acc[4];
    #pragma unroll
    for (int mt = 0; mt < 4; ++mt)
        #pragma unroll
        for (int r = 0; r < 4; ++r) acc[mt][r] = 0.f;

    #pragma unroll
    for (int half = 0; half < 2; ++half) {
        // stage (transpose + hi/lo split), accumulate sumsq
        #pragma unroll
        for (int p = 0; p < 4; ++p) {
            int pp = half * 4 + p;
            int cl = p * 16 + crow;            // 0..63 within stage
            float vv[4] = {q[pp].x, q[pp].y, q[pp].z, q[pp].w};
            ss0 = fmaf(vv[0], vv[0], ss0); ss1 = fmaf(vv[1], vv[1], ss1);
            ss2 = fmaf(vv[2], vv[2], ss2); ss3 = fmaf(vv[3], vv[3], ss3);
            #pragma unroll
            for (int j = 0; j < 4; ++j) {
                unsigned short h = f2bf(vv[j]);
                shh[(nseg + j) * SPITCH + cl] = h;
                shl[(nseg + j) * SPITCH + cl] = f2bf(vv[j] - bf2f(h));
            }
        }
        // MFMA over this half (reads only this wave's own stage rows)
        #pragma unroll
        for (int ks2 = 0; ks2 < 2; ++ks2) {
            bf16x8 bh = *reinterpret_cast<const bf16x8*>(
                &shh[lid * SPITCH + ks2 * 32 + quad * 8]);
            bf16x8 bl = *reinterpret_cast<const bf16x8*>(
                &shl[lid * SPITCH + ks2 * 32 + quad * 8]);
            int cg = half * 64 + ks2 * 32;
            #pragma unroll
            for (int mt = 0; mt < 4; ++mt) {
                bf16x8 ah = *reinterpret_cast<const bf16x8*>(
                    wha + (size_t)mt * 16 * C_ + cg);
                bf16x8 al = *reinterpret_cast<const bf16x8*>(
                    wla + (size_t)mt * 16 * C_ + cg);
                acc[mt] = __builtin_amdgcn_mfma_f32_16x16x32_bf16(ah, bh, acc[mt], 0, 0, 0);
                acc[mt] = __builtin_amdgcn_mfma_f32_16x16x32_bf16(al, bh, acc[mt], 0, 0, 0);
                acc[mt] = __builtin_amdgcn_mfma_f32_16x16x32_bf16(ah, bl, acc[mt], 0, 0, 0);
            }
        }
    }
    // reduce sumsq over same-nseg lanes (stride-4 within wave)
    #pragma unroll
    for (int m = 4; m <= 32; m <<= 1) {
        ss0 += __shfl_xor(ss0, m, 64); ss1 += __shfl_xor(ss1, m, 64);
        ss2 += __shfl_xor(ss2, m, 64); ss3 += __shfl_xor(ss3, m, 64);
    }
    if (L < 4) {
        ssq[w][L * 4 + 0] = ss0; ssq[w][L * 4 + 1] = ss1;
        ssq[w][L * 4 + 2] = ss2; ssq[w][L * 4 + 3] = ss3;
    }
    __syncthreads();   // all waves done with stage -> reuse as red
    {
        float* rp = red + w * (16 * 68);
        #pragma unroll
        for (int mt = 0; mt < 4; ++mt)
            *reinterpret_cast<f32x4*>(&rp[lid * 68 + mt * 16 + quad * 4]) = acc[mt];
    }
    __syncthreads();

    // ---- softmax: wave w handles n rows w*4..w*4+3; lane L = k (lockstep rows)
    float vv[4], iv[4];
    #pragma unroll
    for (int i = 0; i < 4; ++i) {
        int n = w * 4 + i;
        float s = ssq[0][n] + ssq[1][n] + ssq[2][n] + ssq[3][n];
        iv[i] = 1.0f / fmaxf(sqrtf(s), EPSV);
        float v = red[0 * 1088 + n * 68 + L] + red[1 * 1088 + n * 68 + L]
                + red[2 * 1088 + n * 68 + L] + red[3 * 1088 + n * 68 + L];
        vv[i] = fmaf(v, iv[i], bk);
    }
    float mx[4] = {vv[0], vv[1], vv[2], vv[3]};
    #pragma unroll
    for (int m = 1; m <= 32; m <<= 1) {
        #pragma unroll
        for (int i = 0; i < 4; ++i) mx[i] = fmaxf(mx[i], __shfl_xor(mx[i], m, 64));
    }
    float e[4], se[4];
    #pragma unroll
    for (int i = 0; i < 4; ++i) { e[i] = __expf(vv[i] - mx[i]); se[i] = e[i]; }
    #pragma unroll
    for (int m = 1; m <= 32; m <<= 1) {
        #pragma unroll
        for (int i = 0; i < 4; ++i) se[i] += __shfl_xor(se[i], m, 64);
    }
    float asl = 0.f;
    unsigned short av[4];
    #pragma unroll
    for (int i = 0; i < 4; ++i) {
        float a = e[i] / se[i];
        av[i] = f2bf(a * iv[i]);
        asl += a;
    }
    atomicAdd(&asum[t * 64 + L], asl);
    ushort4 st; st.x = av[0]; st.y = av[1]; st.z = av[2]; st.w = av[3];
    *reinterpret_cast<ushort4*>(aT + ((size_t)t * 64 + L) * NA_ + n0 + w * 4) = st;
    // fused tail-zero (n=784..800) replaces the aT memset
    if (blockIdx.x == 48) {
        ushort4 z; z.x = 0; z.y = 0; z.z = 0; z.w = 0;
        *reinterpret_cast<ushort4*>(aT + ((size_t)t * 64 + L) * NA_ + 784 + w * 4) = z;
    }
}

// vlad[t][k][c] = sum_n ahat[k][n]*x[c][n] - asum[k]*cent[k][c]; g2 partial fused.
// v6: split over k-halves (grid 32 x 2 x 30 = 1920 blocks, 7.5/CU):
// disjoint vlad stores (no atomics, no second buffer), per-block 2 MFMA tiles.
// x read as fp32 (L3-resident after k_assign).
__global__ __launch_bounds__(256, 4) void k_vlad(
    const float* __restrict__ x, const unsigned short* __restrict__ aT,
    const float* __restrict__ asum, const float* __restrict__ cent,
    float* __restrict__ vlad, float* __restrict__ g2)
{
    __shared__ float red[4][16 * 36];   // [wave][c(16) x k(32)+pad4]
    int t = blockIdx.z, kh = blockIdx.y, c0 = blockIdx.x * 16;
    int tid = threadIdx.x;
    int w = tid >> 6, L = tid & 63, lid = L & 15, quad = L >> 4;

    f32x4 acc[2];
    #pragma unroll
    for (int mt = 0; mt < 2; ++mt)
        #pragma unroll
        for (int r = 0; r < 4; ++r) acc[mt][r] = 0.f;

    const float* xrow = x + ((size_t)t * C_ + c0 + lid) * N_;
    const unsigned short* a0 = aT + ((size_t)t * 64 + kh * 32 + lid) * NA_;

    // epilogue operands issued early: thread -> (k_loc, 2 c's)
    int k_loc = tid >> 3, j8 = tid & 7, ce = j8 * 2;
    int kg = kh * 32 + k_loc;
    float as = asum[t * 64 + kg];
    float2 cv = *reinterpret_cast<const float2*>(cent + kg * C_ + c0 + ce);

    // prologue: load step s0 = w
    int nb = w * 32 + quad * 8;
    int nc = nb > 776 ? 776 : nb;   // clamped lanes hit aT zeros
    float4 x0c = *reinterpret_cast<const float4*>(xrow + nc);
    float4 x1c = *reinterpret_cast<const float4*>(xrow + nc + 4);
    bf16x8 f0 = *reinterpret_cast<const bf16x8*>(a0 + nb);
    bf16x8 f1 = *reinterpret_cast<const bf16x8*>(a0 + 16 * NA_ + nb);

    for (int s = w; s < 25; s += 4) {
        int sn = s + 4;
        float4 x0n = x0c, x1n = x1c;
        bf16x8 g0 = f0, g1 = f1;
        if (sn < 25) {  // wave-uniform: prefetch next step
            int nb2 = sn * 32 + quad * 8;
            int nc2 = nb2 > 776 ? 776 : nb2;
            x0n = *reinterpret_cast<const float4*>(xrow + nc2);
            x1n = *reinterpret_cast<const float4*>(xrow + nc2 + 4);
            g0  = *reinterpret_cast<const bf16x8*>(a0 + nb2);
            g1  = *reinterpret_cast<const bf16x8*>(a0 + 16 * NA_ + nb2);
        }
        bf16x8 bb;
        bb[0] = (short)f2bf(x0c.x); bb[1] = (short)f2bf(x0c.y);
        bb[2] = (short)f2bf(x0c.z); bb[3] = (short)f2bf(x0c.w);
        bb[4] = (short)f2bf(x1c.x); bb[5] = (short)f2bf(x1c.y);
        bb[6] = (short)f2bf(x1c.z); bb[7] = (short)f2bf(x1c.w);
        acc[0] = __builtin_amdgcn_mfma_f32_16x16x32_bf16(f0, bb, acc[0], 0, 0, 0);
        acc[1] = __builtin_amdgcn_mfma_f32_16x16x32_bf16(f1, bb, acc[1], 0, 0, 0);
        x0c = x0n; x1c = x1n; f0 = g0; f1 = g1;
    }
    {
        float* rp = &red[w][0];
        #pragma unroll
        for (int mt = 0; mt < 2; ++mt)
            *reinterpret_cast<f32x4*>(&rp[lid * 36 + mt * 16 + quad * 4]) = acc[mt];
    }
    __syncthreads();

    // epilogue: v for (kg, ce..ce+1); fused g2 partial
    float2 vout;
    float s2 = 0.f;
    #pragma unroll
    for (int j = 0; j < 2; ++j) {
        int cc = ce + j;
        float v = red[0][cc * 36 + k_loc] + red[1][cc * 36 + k_loc]
                + red[2][cc * 36 + k_loc] + red[3][cc * 36 + k_loc];
        v -= as * ((const float*)&cv)[j];
        ((float*)&vout)[j] = v;
        s2 = fmaf(v, v, s2);
    }
    *reinterpret_cast<float2*>(vlad + ((size_t)t * 64 + kg) * C_ + c0 + ce) = vout;
    s2 += __shfl_xor(s2, 1, 64);
    s2 += __shfl_xor(s2, 2, 64);
    s2 += __shfl_xor(s2, 4, 64);
    if (j8 == 0) atomicAdd(&g2[t * 64 + kg], s2);
}

// out[k*512+c] = sum_t vlad * inv_intra * inv_g. t split over 2 thread-halves
// (grid 256 blocks, 128 idx each) for 2x parallelism + half-depth load chains.
__global__ __launch_bounds__(256) void k_out(
    const float* __restrict__ vlad, const float* __restrict__ g2,
    float* __restrict__ out)
{
    __shared__ float intr[1920];
    __shared__ float gl[1920];
    __shared__ float sinv[T_];
    __shared__ float part[256];
    int tid = threadIdx.x;
    for (int i = tid; i < 1920; i += 256) {
        float s = g2[i];
        gl[i] = s;
        intr[i] = 1.0f / fmaxf(sqrtf(s), EPSV);
    }
    __syncthreads();
    if (tid < T_) {
        float s = 0.f;
        #pragma unroll 8
        for (int k = 0; k < 64; ++k) {
            float iv = intr[tid * 64 + k];
            s += gl[tid * 64 + k] * iv * iv;
        }
        sinv[tid] = 1.0f / fmaxf(sqrtf(s), EPSV);
    }
    __syncthreads();
    int idx = blockIdx.x * 128 + (tid & 127);  // k*512+c
    int th = tid >> 7;
    int k = idx >> 9;
    float s = 0.f;
    #pragma unroll
    for (int t = th * 15; t < th * 15 + 15; ++t)
        s += vlad[(size_t)t * 32768 + idx] * intr[t * 64 + k] * sinv[t];
    part[tid] = s;
    __syncthreads();
    if (tid < 128) out[idx] = part[tid] + part[tid + 128];
}

extern "C" void kernel_launch(void* const* d_in, const int* in_sizes, int n_in,
                              void* d_out, int out_size, void* d_ws, size_t ws_size,
                              hipStream_t stream) {
    const float* x    = (const float*)d_in[0];   // 30*512*784
    const float* cent = (const float*)d_in[1];   // 64*512
    const float* w    = (const float*)d_in[2];   // 64*512
    const float* b    = (const float*)d_in[3];   // 64
    float* out = (float*)d_out;

    char* p = (char*)d_ws;
    unsigned short* wh = (unsigned short*)p;  p += 65536;
    unsigned short* wl = (unsigned short*)p;  p += 65536;
    float* asum = (float*)p;                  p += 1920 * 4;
    float* g2   = (float*)p;                  p += 1920 * 4;
    float* vlad = (float*)p;                  p += (size_t)T_ * 64 * C_ * 4;   // 3,932,160
    unsigned short* aT = (unsigned short*)p;  p += (size_t)T_ * 64 * NA_ * 2;  // 3,072,000
    // total ~= 7.2 MB

    k_prep<<<128, 256, 0, stream>>>(w, wh, wl);
    hipMemsetAsync(asum, 0, 2 * 1920 * 4, stream);   // asum + g2 (15 KB only)
    k_assign<<<dim3(49, T_), 256, 0, stream>>>(x, wh, wl, b, aT, asum);
    k_vlad<<<dim3(32, 2, T_), 256, 0, stream>>>(x, aT, asum, cent, vlad, g2);
    k_out<<<256, 256, 0, stream>>>(vlad, g2, out);
}